// Round 9
// baseline (1007.917 us; speedup 1.0000x reference)
//
#include <hip/hip_runtime.h>
#include <cstdint>
#include <cmath>

typedef _Float16 f16;
typedef _Float16 f16x8 __attribute__((ext_vector_type(8)));
typedef _Float16 f16x4 __attribute__((ext_vector_type(4)));
typedef float f32x4 __attribute__((ext_vector_type(4)));

// async 16B/lane global->LDS (lds dst = wave-uniform base + lane*16)
__device__ inline void gld_lds16(const void* g, void* l) {
  __builtin_amdgcn_global_load_lds(
      (__attribute__((address_space(1))) void*)(uintptr_t)g,
      (__attribute__((address_space(3))) void*)l, 16, 0, 0);
}

// ---------------------------------------------------------------------------
// Software grid barrier (graph-capture-safe; NO cooperative launch).
// Safety: grid must be <= co-resident capacity (audited per kernel below).
// Release: __threadfence before arrival-add. Acquire: fence after observing
// full count. Counter zeroed by prep_kernel earlier in the same stream.
__device__ inline void gbar(int* cnt, int nblk) {
  __syncthreads();
  __threadfence();
  if (threadIdx.x == 0) {
    __hip_atomic_fetch_add(cnt, 1, __ATOMIC_ACQ_REL, __HIP_MEMORY_SCOPE_AGENT);
    while (__hip_atomic_load(cnt, __ATOMIC_ACQUIRE, __HIP_MEMORY_SCOPE_AGENT) < nblk)
      __builtin_amdgcn_s_sleep(8);
  }
  __syncthreads();
  __threadfence();
}

// ---------------------------------------------------------------------------
// prep: fused build_x1 (jobs 0..5887) + wsum_t (jobs 5888..6079) + zero the
// grid-barrier counters (job 0).
__global__ __launch_bounds__(256) void prep_kernel(
    const float* __restrict__ enc, const float* __restrict__ word,
    const float* __restrict__ pers, const int* __restrict__ speaker,
    const float* __restrict__ h0, f16* __restrict__ X,
    const float* __restrict__ W2, const float* __restrict__ U2,
    const float* __restrict__ W3, const float* __restrict__ U3,
    const float* __restrict__ W4, const float* __restrict__ U4,
    f16* __restrict__ wout, int* __restrict__ cnts)
{
  const int job = blockIdx.x;
  if (job == 0 && threadIdx.x < 8) cnts[threadIdx.x] = 0;
  if (job < 5888) {
    const int b  = job / 23;
    const int k2 = (job % 23) * 256 + threadIdx.x;   // 0..5887
    const int k  = k2 * 2;
    float v0, v1;
    if (k < 10240) {
      const float* p = enc + (long long)b * 10240 + k; v0 = p[0]; v1 = p[1];
    } else if (k < 10752) {
      const float* p = word + b * 512 + (k - 10240);   v0 = p[0]; v1 = p[1];
    } else if (k < 11264) {
      const float* p = pers + (long long)speaker[b] * 512 + (k - 10752); v0 = p[0]; v1 = p[1];
    } else {
      const float* p = h0 + b * 512 + (k - 11264);     v0 = p[0]; v1 = p[1];
    }
    union { f16 h[2]; unsigned int u; } pk;
    pk.h[0] = (f16)v0; pk.h[1] = (f16)v1;
    ((unsigned int*)X)[(long long)b * 5888 + k2] = pk.u;
  } else {
    const int w = job - 5888;                 // 0..191
    const int t = (w & 63) * 256 + threadIdx.x;
    const int L = w >> 6;
    const float* W = (L == 0) ? W2 : (L == 1) ? W3 : W4;
    const float* U = (L == 0) ? U2 : (L == 1) ? U3 : U4;
    const int n  = t & 2047;
    const int k0 = (t >> 11) << 6;
    f16* op = wout + (long long)L * (2048 * 512) + (long long)n * 512 + k0;
    for (int kk = 0; kk < 64; kk += 8) {
      f16x8 v;
      #pragma unroll
      for (int j = 0; j < 8; j++) {
        const int k = k0 + kk + j;
        v[j] = (f16)(W[(long long)k * 2048 + n] + U[(long long)k * 2048 + n]);
      }
      *(f16x8*)(op + kk) = v;
    }
  }
}

// ---------------------------------------------------------------------------
// Small LSTM layer tile (device fn): one wave computes 16m x 16j x 4 gates,
// K=512, barrier-free, SSA register double buffer (proven kernel body).
__device__ void lstm_tile(
    int wid, int lane,
    const f16* __restrict__ h_in, const f16* __restrict__ WsT,
    const float* __restrict__ bias,
    const float* __restrict__ c_prev, float* __restrict__ c_out,
    f16* __restrict__ h16_out, float* __restrict__ h32_out)
{
  const int jt = wid & 31, mt = wid >> 5;   // mt 0..15
  const int m0 = mt * 16, j0 = jt * 16;
  const int lj = lane & 15, quad = lane >> 4;

  const f16* Ab = h_in + (long long)(m0 + lj) * 512 + quad * 8;
  const f16* Bb = WsT + (long long)(j0 + lj) * 512 + quad * 8;
  const long long GS = 512LL * 512;

  f32x4 g0 = {}, g1 = {}, g2 = {}, g3 = {};

  f16x8 ca = *(const f16x8*)(Ab);
  f16x8 cb0 = *(const f16x8*)(Bb);
  f16x8 cb1 = *(const f16x8*)(Bb + GS);
  f16x8 cb2 = *(const f16x8*)(Bb + 2 * GS);
  f16x8 cb3 = *(const f16x8*)(Bb + 3 * GS);

  #pragma unroll
  for (int kt = 0; kt < 16; kt++) {
    f16x8 na = ca, nb0 = cb0, nb1 = cb1, nb2 = cb2, nb3 = cb3;
    if (kt < 15) {
      const int k = (kt + 1) * 32;
      na  = *(const f16x8*)(Ab + k);
      nb0 = *(const f16x8*)(Bb + k);
      nb1 = *(const f16x8*)(Bb + GS + k);
      nb2 = *(const f16x8*)(Bb + 2 * GS + k);
      nb3 = *(const f16x8*)(Bb + 3 * GS + k);
    }
    g0 = __builtin_amdgcn_mfma_f32_16x16x32_f16(ca, cb0, g0, 0, 0, 0);
    g1 = __builtin_amdgcn_mfma_f32_16x16x32_f16(ca, cb1, g1, 0, 0, 0);
    g2 = __builtin_amdgcn_mfma_f32_16x16x32_f16(ca, cb2, g2, 0, 0, 0);
    g3 = __builtin_amdgcn_mfma_f32_16x16x32_f16(ca, cb3, g3, 0, 0, 0);
    ca = na; cb0 = nb0; cb1 = nb1; cb2 = nb2; cb3 = nb3;
  }

  const float bi = bias[j0 + lj],        bfv = bias[512 + j0 + lj];
  const float bg = bias[1024 + j0 + lj], bo  = bias[1536 + j0 + lj];
  #pragma unroll
  for (int r = 0; r < 4; r++) {
    const int m = m0 + quad * 4 + r;
    const int idx = m * 512 + j0 + lj;
    const float gi = 1.f / (1.f + expf(-(g0[r] + bi)));
    const float gf = 1.f / (1.f + expf(-(g1[r] + bfv)));
    const float gg = fmaxf(g2[r] + bg, 0.f);
    const float go = 1.f / (1.f + expf(-(g3[r] + bo)));
    const float cn = gf * c_prev[idx] + gi * gg;
    const float hn = go * fmaxf(cn, 0.f);
    c_out[idx] = cn;
    h16_out[idx] = (f16)hn;
    if (h32_out) h32_out[idx] = hn;
  }
}

// ---------------------------------------------------------------------------
// mid: L1 GEMM (R6-verified structure, XCD co-location, NO rotation) ->
// gbar -> gate -> gbar -> L2 -> gbar -> L3 -> gbar -> L4.
// 384 blocks x 256 thr, LDS 53248 B -> 3 blocks/CU -> capacity 768 >= 384:
// all blocks co-resident, software barrier is safe. Every block reaches
// every gbar (inactive blocks skip work only; all __syncthreads are
// block-uniform).
__global__ __launch_bounds__(256, 2) void mid_kernel(
    const f16* __restrict__ X1h, const float* __restrict__ W1,
    const float* __restrict__ U1, f16* __restrict__ zp16,
    const float* __restrict__ b1, const float* __restrict__ c0,
    float* __restrict__ cbuf, f16* __restrict__ hA, f16* __restrict__ hB,
    f16* __restrict__ hC, const f16* __restrict__ WsT,
    const float* __restrict__ b2, const float* __restrict__ b3,
    const float* __restrict__ b4, float* __restrict__ c4_out,
    float* __restrict__ h4_out, int* __restrict__ cnts)
{
  __shared__ __align__(16) f16 Ah[2][256 * 32];   // 2 x 16 KB
  __shared__ __align__(16) f16 Bh[2][128 * 40];   // 2 x 10 KB

  const int tid  = threadIdx.x;
  const int lane = tid & 63;
  const int wave = tid >> 6;

  // ---- stage 1: L1 GEMM, K = 11776 = 23 splits x 512 (16 iters) ----
  {
    const int f   = blockIdx.x;     // 384 = 8 xcd * 16 nt * 3 groups
    const int xcd = f & 7;
    const int j   = f >> 3;
    const int g   = j >> 4;
    const int nt  = j & 15;
    const int s   = g * 8 + xcd;
    if (s < 23) {
      const int n0 = nt * 128;
      const int kbeg = s * 512;
      const int a_row16 = lane >> 2;
      const int a_ksub  = ((lane & 3) ^ ((lane >> 3) & 3)) * 8;
      const int nl0  = lane * 2;
      const int koct = wave;

      float2 bv[8];
      auto issueB = [&](int kt) {
        const int kb = kbeg + kt * 32 + koct * 8;
        #pragma unroll
        for (int i = 0; i < 8; i++) {
          const int krow = kb + i;
          const float* bp = (krow >= 11264) ? (U1 + (long long)(krow - 11264) * 2048)
                                            : (W1 + (long long)krow * 2048);
          bv[i] = *(const float2*)(bp + n0 + nl0);
        }
      };
      auto issueA = [&](int kt) {
        const int akb = kbeg + kt * 32;
        #pragma unroll
        for (int half = 0; half < 4; half++) {
          const int rb = wave * 64 + half * 16;
          const f16* gp = X1h + (long long)(rb + a_row16) * 11776 + akb + a_ksub;
          gld_lds16((const void*)gp, (void*)&Ah[kt & 1][rb * 32]);
        }
      };
      auto writeB = [&](int kt) {
        f16x8 p0, p1;
        #pragma unroll
        for (int i = 0; i < 8; i++) { p0[i] = (f16)bv[i].x; p1[i] = (f16)bv[i].y; }
        *(f16x8*)&Bh[kt & 1][(nl0    ) * 40 + koct * 8] = p0;
        *(f16x8*)&Bh[kt & 1][(nl0 + 1) * 40 + koct * 8] = p1;
      };

      const int wm = (wave & 1) * 128;
      const int wn = (wave >> 1) * 64;
      f32x4 acc[8][4] = {};

      issueB(0); issueA(0); writeB(0);
      __syncthreads();
      for (int kt = 0; kt < 16; kt++) {
        const int buf = kt & 1;
        const bool more = (kt + 1 < 16);
        if (more) { issueB(kt + 1); issueA(kt + 1); }
        f16x8 bf[4];
        #pragma unroll
        for (int ni = 0; ni < 4; ni++) {
          const int n = wn + ni * 16 + (lane & 15);
          bf[ni] = *(const f16x8*)&Bh[buf][n * 40 + (lane >> 4) * 8];
        }
        #pragma unroll
        for (int mi = 0; mi < 8; mi++) {
          const int m = wm + mi * 16 + (lane & 15);
          const f16x8 af = *(const f16x8*)&Ah[buf][m * 32 + (((lane >> 4) ^ ((m >> 1) & 3)) * 8)];
          #pragma unroll
          for (int ni = 0; ni < 4; ni++)
            acc[mi][ni] = __builtin_amdgcn_mfma_f32_16x16x32_f16(af, bf[ni], acc[mi][ni], 0, 0, 0);
        }
        if (more) writeB(kt + 1);
        __syncthreads();
      }
      f16* Cs = zp16 + (long long)s * 524288;
      #pragma unroll
      for (int mi = 0; mi < 8; mi++) {
        const int r0 = wm + mi * 16 + (lane >> 4) * 4;
        #pragma unroll
        for (int ni = 0; ni < 4; ni++) {
          const int cc = n0 + wn + ni * 16 + (lane & 15);
          #pragma unroll
          for (int r = 0; r < 4; r++)
            Cs[(long long)(r0 + r) * 2048 + cc] = (f16)acc[mi][ni][r];
        }
      }
    }
  }
  gbar(&cnts[0], 384);

  // ---- stage 2: gate (reduce 23 splits + bias, apply gates) ----
  {
    const int idx2 = blockIdx.x * 256 + tid;   // 0..98303; active < 65536
    if (idx2 < 65536) {
      const unsigned int* zb = (const unsigned int*)zp16;
      const int b  = idx2 >> 8;
      const int j2 = idx2 & 255;
      const int jj = j2 * 2;
      float z[4][2];
      #pragma unroll
      for (int g = 0; g < 4; g++) { z[g][0] = b1[g * 512 + jj]; z[g][1] = b1[g * 512 + jj + 1]; }
      #pragma unroll 2
      for (int s = 0; s < 23; s++) {
        const unsigned int* zp = zb + (long long)s * 262144 + b * 1024;
        #pragma unroll
        for (int g = 0; g < 4; g++) {
          union { unsigned int u; f16 h[2]; } v;
          v.u = zp[g * 256 + j2];
          z[g][0] += (float)v.h[0];
          z[g][1] += (float)v.h[1];
        }
      }
      #pragma unroll
      for (int e = 0; e < 2; e++) {
        const float gi = 1.f / (1.f + expf(-z[0][e]));
        const float gf = 1.f / (1.f + expf(-z[1][e]));
        const float gg = fmaxf(z[2][e], 0.f);
        const float go = 1.f / (1.f + expf(-z[3][e]));
        const int idx = b * 512 + jj + e;
        const float cn = gf * c0[idx] + gi * gg;
        const float hn = go * fmaxf(cn, 0.f);
        cbuf[idx] = cn;
        hA[idx] = (f16)hn;
      }
    }
  }
  gbar(&cnts[1], 384);

  // ---- stages 3-5: LSTM layers 2-4 (512 wave-tiles each) ----
  const long long LW = 2048LL * 512;
  const int wid = blockIdx.x * 4 + wave;       // 0..1535; active < 512
  if (wid < 512) lstm_tile(wid, lane, hA, WsT,          b2, cbuf, cbuf, hB, nullptr);
  gbar(&cnts[2], 384);
  if (wid < 512) lstm_tile(wid, lane, hB, WsT + LW,     b3, cbuf, cbuf, hA, nullptr);
  gbar(&cnts[3], 384);
  if (wid < 512) lstm_tile(wid, lane, hA, WsT + 2 * LW, b4, cbuf, c4_out, hC, h4_out);
}

// ---------------------------------------------------------------------------
// dec: decoder GEMM (f16 logits, XCD-chunked nt) -> gbar -> fused softmax
// (1 row/block, 3 passes, row L2-hot). 256 blocks x 256 thr, LDS 53280 B
// -> 3 blocks/CU -> capacity 768 >= 256: co-residency guaranteed.
__global__ __launch_bounds__(256, 2) void dec_kernel(
    const f16* __restrict__ hC, const float* __restrict__ Wd,
    f16* __restrict__ zdec, const float* __restrict__ bd,
    float* __restrict__ out, int* __restrict__ cnts)
{
  __shared__ __align__(16) f16 Ah[2][256 * 32];
  __shared__ __align__(16) f16 Bh[2][128 * 40];
  __shared__ float redA[4];
  __shared__ float redB[4];

  const int tid  = threadIdx.x;
  const int lane = tid & 63;
  const int wave = tid >> 6;

  // ---- stage 1: logits = hC(256x512 f16) @ Wd(512x32000 f32) -> f16 ----
  {
    const int f   = blockIdx.x;      // 256 = 8 xcd * 32
    const int xcd = f & 7;
    const int j   = f >> 3;
    const int nt  = xcd * 32 + j;    // chunked: 32 consecutive tiles per XCD
    if (nt < 250) {
      const int n0 = nt * 128;
      const int a_row16 = lane >> 2;
      const int a_ksub  = ((lane & 3) ^ ((lane >> 3) & 3)) * 8;
      const int nl0  = lane * 2;
      const int koct = wave;

      float2 bv[8];
      auto issueB = [&](int kt) {
        const int kb = kt * 32 + koct * 8;
        #pragma unroll
        for (int i = 0; i < 8; i++) {
          const float* bp = Wd + (long long)(kb + i) * 32000;
          bv[i] = *(const float2*)(bp + n0 + nl0);
        }
      };
      auto issueA = [&](int kt) {
        const int akb = kt * 32;
        #pragma unroll
        for (int half = 0; half < 4; half++) {
          const int rb = wave * 64 + half * 16;
          const f16* gp = hC + (long long)(rb + a_row16) * 512 + akb + a_ksub;
          gld_lds16((const void*)gp, (void*)&Ah[kt & 1][rb * 32]);
        }
      };
      auto writeB = [&](int kt) {
        f16x8 p0, p1;
        #pragma unroll
        for (int i = 0; i < 8; i++) { p0[i] = (f16)bv[i].x; p1[i] = (f16)bv[i].y; }
        *(f16x8*)&Bh[kt & 1][(nl0    ) * 40 + koct * 8] = p0;
        *(f16x8*)&Bh[kt & 1][(nl0 + 1) * 40 + koct * 8] = p1;
      };

      const int wm = (wave & 1) * 128;
      const int wn = (wave >> 1) * 64;
      f32x4 acc[8][4] = {};

      issueB(0); issueA(0); writeB(0);
      __syncthreads();
      for (int kt = 0; kt < 16; kt++) {
        const int buf = kt & 1;
        const bool more = (kt + 1 < 16);
        if (more) { issueB(kt + 1); issueA(kt + 1); }
        f16x8 bf[4];
        #pragma unroll
        for (int ni = 0; ni < 4; ni++) {
          const int n = wn + ni * 16 + (lane & 15);
          bf[ni] = *(const f16x8*)&Bh[buf][n * 40 + (lane >> 4) * 8];
        }
        #pragma unroll
        for (int mi = 0; mi < 8; mi++) {
          const int m = wm + mi * 16 + (lane & 15);
          const f16x8 af = *(const f16x8*)&Ah[buf][m * 32 + (((lane >> 4) ^ ((m >> 1) & 3)) * 8)];
          #pragma unroll
          for (int ni = 0; ni < 4; ni++)
            acc[mi][ni] = __builtin_amdgcn_mfma_f32_16x16x32_f16(af, bf[ni], acc[mi][ni], 0, 0, 0);
        }
        if (more) writeB(kt + 1);
        __syncthreads();
      }
      #pragma unroll
      for (int mi = 0; mi < 8; mi++) {
        const int r0 = wm + mi * 16 + (lane >> 4) * 4;
        #pragma unroll
        for (int ni = 0; ni < 4; ni++) {
          const int cc = n0 + wn + ni * 16 + (lane & 15);
          #pragma unroll
          for (int r = 0; r < 4; r++)
            zdec[(long long)(r0 + r) * 32000 + cc] = (f16)acc[mi][ni][r];
        }
      }
    }
  }
  gbar(&cnts[4], 256);

  // ---- stage 2: softmax, row = blockIdx.x, 256 thr, 3 passes ----
  {
    const int row = blockIdx.x;
    const f16x4* zp = (const f16x4*)(zdec + (long long)row * 32000);
    const float4* bp = (const float4*)bd;
    float4* rp = (float4*)(out + (long long)row * 32000);

    float m = -1e30f;
    for (int i = 0; i < 32; i++) {
      const int v = tid + i * 256;
      if (v < 8000) {
        const f16x4 a = zp[v]; const float4 bb = bp[v];
        const float x0 = (float)a[0] + bb.x, x1 = (float)a[1] + bb.y;
        const float x2 = (float)a[2] + bb.z, x3 = (float)a[3] + bb.w;
        m = fmaxf(m, fmaxf(fmaxf(x0, x1), fmaxf(x2, x3)));
      }
    }
    #pragma unroll
    for (int off = 32; off > 0; off >>= 1) m = fmaxf(m, __shfl_xor(m, off, 64));
    if (lane == 0) redA[wave] = m;
    __syncthreads();
    const float bm = fmaxf(fmaxf(redA[0], redA[1]), fmaxf(redA[2], redA[3]));

    float s = 0.f;
    for (int i = 0; i < 32; i++) {
      const int v = tid + i * 256;
      if (v < 8000) {
        const f16x4 a = zp[v]; const float4 bb = bp[v];
        s += expf((float)a[0] + bb.x - bm) + expf((float)a[1] + bb.y - bm)
           + expf((float)a[2] + bb.z - bm) + expf((float)a[3] + bb.w - bm);
      }
    }
    #pragma unroll
    for (int off = 32; off > 0; off >>= 1) s += __shfl_xor(s, off, 64);
    if (lane == 0) redB[wave] = s;
    __syncthreads();
    const float inv = 1.0f / (redB[0] + redB[1] + redB[2] + redB[3]);

    for (int i = 0; i < 32; i++) {
      const int v = tid + i * 256;
      if (v < 8000) {
        const f16x4 a = zp[v]; const float4 bb = bp[v];
        float4 x;
        x.x = expf((float)a[0] + bb.x - bm) * inv;
        x.y = expf((float)a[1] + bb.y - bm) * inv;
        x.z = expf((float)a[2] + bb.z - bm) * inv;
        x.w = expf((float)a[3] + bb.w - bm) * inv;
        rp[v] = x;
      }
    }
  }
}

// ---------------------------------------------------------------------------
extern "C" void kernel_launch(void* const* d_in, const int* in_sizes, int n_in,
                              void* d_out, int out_size, void* d_ws, size_t ws_size,
                              hipStream_t stream) {
  const float* enc     = (const float*)d_in[0];
  const float* word    = (const float*)d_in[1];
  const float* h0      = (const float*)d_in[2];
  const float* c0      = (const float*)d_in[3];
  const int*   speaker = (const int*)d_in[4];
  const float* pers = (const float*)d_in[6];
  const float* W1 = (const float*)d_in[7];
  const float* U1 = (const float*)d_in[8];
  const float* b1 = (const float*)d_in[9];
  const float* W2 = (const float*)d_in[10];
  const float* U2 = (const float*)d_in[11];
  const float* b2 = (const float*)d_in[12];
  const float* W3 = (const float*)d_in[13];
  const float* U3 = (const float*)d_in[14];
  const float* b3 = (const float*)d_in[15];
  const float* W4 = (const float*)d_in[16];
  const float* U4 = (const float*)d_in[17];
  const float* b4 = (const float*)d_in[18];
  const float* Wd = (const float*)d_in[19];
  const float* bd = (const float*)d_in[20];

  float* out = (float*)d_out;
  float* h4_out = out + 8192000;
  float* c4_out = out + 8192000 + 131072;

  // d_ws layout (harness provides ~352 MB):
  f16*   hA   = (f16*)d_ws;                            // 256 KB
  f16*   hB   = (f16*)((char*)d_ws + 262144);          // 256 KB
  f16*   hC   = (f16*)((char*)d_ws + 524288);          // 256 KB
  float* cbuf = (float*)((char*)d_ws + 786432);        // 512 KB
  int*   cnts = (int*)((char*)d_ws + 1310720);         // 32 B barrier counters
  f16*   WsT  = (f16*)((char*)d_ws + 2097152);         // 6 MB  [2..8 MB)
  f16*   X1h  = (f16*)((char*)d_ws + 8388608);         // 6 MB  [8..14.1 MB)
  f16*   zp16 = (f16*)((char*)d_ws + 16777216);        // 24 MB [16..40 MB)
  f16*   zdec = (f16*)((char*)d_ws + 50331648);        // 16.4 MB [48..64.4 MB)

  // 1) prep: build X1 + WsT + zero barrier counters
  prep_kernel<<<dim3(6080), 256, 0, stream>>>(
      enc, word, pers, speaker, h0, X1h, W2, U2, W3, U3, W4, U4, WsT, cnts);

  // 2) mid: L1 gemm -> gate -> L2 -> L3 -> L4 (software grid barriers)
  mid_kernel<<<dim3(384), 256, 0, stream>>>(
      X1h, W1, U1, zp16, b1, c0, cbuf, hA, hB, hC, WsT, b2, b3, b4,
      c4_out, h4_out, cnts);

  // 3) dec: decoder gemm -> softmax (software grid barrier)
  dec_kernel<<<dim3(256), 256, 0, stream>>>(hC, Wd, zdec, bd, out, cnts);
}